// Round 9
// baseline (60.257 us; speedup 1.0000x reference)
//
#include <hip/hip_runtime.h>
#include <math.h>

#define FN 50
#define CARD 10000
#define NP 1225          // F*(F-1)/2
#define NTILE 77         // ceil(NP/16)
#define NPAD (NTILE*16)  // 1232
#define FSTRIDE 72       // halves per factor row (144 B)

typedef _Float16 half8 __attribute__((ext_vector_type(8)));
typedef __fp16 half2t __attribute__((ext_vector_type(2)));
typedef float floatx4 __attribute__((ext_vector_type(4)));

static __device__ __forceinline__ half2t h2max0(half2t v) {
  half2t r;
  r[0] = v[0] > (__fp16)0 ? v[0] : (__fp16)0;
  r[1] = v[1] > (__fp16)0 ? v[1] : (__fp16)0;
  return r;
}
static __device__ __forceinline__ float hdot2(half2t a, half2t b, float c) {
#if __has_builtin(__builtin_amdgcn_fdot2)
  return __builtin_amdgcn_fdot2(a, b, c, false);
#else
  return c + (float)a[0]*(float)b[0] + (float)a[1]*(float)b[1];
#endif
}

__global__ __launch_bounds__(256, 4)
void afm_kernel(const int* __restrict__ inp,
                const float* __restrict__ emb,
                const float* __restrict__ wlin,
                const float* __restrict__ blin,
                const float* __restrict__ W1,
                const float* __restrict__ b1,
                const float* __restrict__ W2,
                const float* __restrict__ b2,
                float* __restrict__ out,
                int nrep)
{
  __shared__ __align__(16) _Float16 s_fac[FN][FSTRIDE];   // 7200 B
  __shared__ __align__(16) _Float16 s_w1[512 * 8];        // 8192 B, frag layout
  __shared__ __align__(16) unsigned s_pij[NPAD];          // 4928 B (aliased f32 logit in ph2)
  __shared__ __align__(16) __fp16 s_lg4[NPAD * 4];        // 9856 B, per-kq logit partials
  __shared__ float s_pool[NPAD];                          // 4928 B
  __shared__ float s_wl[FN];
  __shared__ float s_red[16];

  const int tid  = threadIdx.x;
  const int b    = blockIdx.x;
  const int lane = tid & 63;
  const int wave = tid >> 6;
  const int c    = lane & 15;
  const int kq   = lane >> 4;

  // ---- phase 0a: pair table (closed form + fixup) ----
  for (int p = tid; p < NPAD; p += 256) {
    int pp = p < NP ? p : NP - 1;
    int i = (int)((99.0f - sqrtf(9801.0f - 8.0f * (float)pp)) * 0.5f);
    if (i < 0) i = 0;
    while ((i + 1) * (98 - i) / 2 <= pp) ++i;
    while (i > 0 && i * (99 - i) / 2 > pp) --i;
    int j = pp - i * (99 - i) / 2 + i + 1;
    s_pij[p] = (unsigned)(i * (FSTRIDE * 2)) | ((unsigned)(j * (FSTRIDE * 2)) << 16);
  }

  // ---- phase 0b: factor gather f32 -> f16 LDS ----
  const int* inprow = inp + b * FN;
  for (int idx = tid; idx < FN * 16; idx += 256) {
    int f = idx >> 4, q = idx & 15;
    int flat = inprow[f] + f * CARD;
    floatx4 v = ((const floatx4*)emb)[(long)flat * 16 + q];
    _Float16* dst = &s_fac[f][q * 4];
    dst[0] = (_Float16)v[0]; dst[1] = (_Float16)v[1];
    dst[2] = (_Float16)v[2]; dst[3] = (_Float16)v[3];
  }
  if (tid < FN) {
    int flat = inprow[tid] + tid * CARD;
    s_wl[tid] = wlin[flat];
  }

  // ---- phase 0c: stage W1 into LDS in fragment layout ----
  for (int ch = tid; ch < 512; ch += 256) {
    int ks = ch >> 8, mt = (ch >> 6) & 3, ln = ch & 63;
    int cc = ln & 15, kk = ln >> 4;
    _Float16 tmp[8];
#pragma unroll
    for (int j = 0; j < 8; ++j)
      tmp[j] = (_Float16)W1[(ks * 32 + kk * 8 + j) * 64 + mt * 16 + cc];
    *(half8*)&s_w1[ch * 8] = *(const half8*)tmp;
  }

  // per-lane bias (f32, MFMA C-in) and W2 slice (f16 packed)
  floatx4 bias[4];
  half2t w2h[4][2];
#pragma unroll
  for (int mt = 0; mt < 4; ++mt) {
    bias[mt] = ((const floatx4*)b1)[mt * 4 + kq];
    floatx4 wv = ((const floatx4*)W2)[mt * 4 + kq];
    w2h[mt][0] = __builtin_amdgcn_cvt_pkrtz(wv[0], wv[1]);
    w2h[mt][1] = __builtin_amdgcn_cvt_pkrtz(wv[2], wv[3]);
  }
  _Float16 onev = (c == 0) ? (_Float16)1 : (_Float16)0;
  half8 onesf = {onev, onev, onev, onev, onev, onev, onev, onev};

  __syncthreads();

  // ---- phase 1 (repeated nrep times; idempotent — identical values to disjoint addrs) ----
#define LDW1(ks, mt) (*(const half8*)&s_w1[(((ks) * 4 + (mt)) * 64 + lane) * 8])
  const char* fbase = (const char*)&s_fac[0][0];
  const int koff = kq * 16;

  for (int rep = 0; rep < nrep; ++rep) {
    int t = wave;
    int pcur = t * 16 + c;
    unsigned po = s_pij[pcur];
    int offi = (int)(po & 0xffffu) + koff;
    int offj = (int)(po >> 16) + koff;
    half8 cvi0 = *(const half8*)(fbase + offi);
    half8 cvj0 = *(const half8*)(fbase + offj);
    half8 cvi1 = *(const half8*)(fbase + offi + 64);
    half8 cvj1 = *(const half8*)(fbase + offj + 64);

    while (true) {
      int tn = t + 4;
      int pn = tn * 16 + c; if (pn > NPAD - 1) pn = NPAD - 1;
      unsigned pon = s_pij[pn];               // prefetch pij (next)

      half8 pr0 = cvi0 * cvj0;                // inter, k-slice 0
      half8 pr1 = cvi1 * cvj1;                // k-slice 1

      floatx4 acc[4];
#pragma unroll
      for (int mt = 0; mt < 4; ++mt) {
        acc[mt] = __builtin_amdgcn_mfma_f32_16x16x32_f16(LDW1(0, mt), pr0, bias[mt], 0, 0, 0);
        acc[mt] = __builtin_amdgcn_mfma_f32_16x16x32_f16(LDW1(1, mt), pr1, acc[mt], 0, 0, 0);
      }
      floatx4 accp = __builtin_amdgcn_mfma_f32_16x16x32_f16(onesf, pr0, (floatx4){0.f,0.f,0.f,0.f}, 0, 0, 0);
      accp = __builtin_amdgcn_mfma_f32_16x16x32_f16(onesf, pr1, accp, 0, 0, 0);

      // prefetch next tile's fragments under the epilogue
      int offi_n = (int)(pon & 0xffffu) + koff;
      int offj_n = (int)(pon >> 16) + koff;
      cvi0 = *(const half8*)(fbase + offi_n);
      cvj0 = *(const half8*)(fbase + offj_n);
      cvi1 = *(const half8*)(fbase + offi_n + 64);
      cvj1 = *(const half8*)(fbase + offj_n + 64);

      // epilogue: relu (bias already in acc) + W2 dot, f16-packed; no cross-lane
      float lg = 0.f;
#pragma unroll
      for (int mt = 0; mt < 4; ++mt) {
        half2t h0 = __builtin_amdgcn_cvt_pkrtz(acc[mt][0], acc[mt][1]);
        half2t h1 = __builtin_amdgcn_cvt_pkrtz(acc[mt][2], acc[mt][3]);
        h0 = h2max0(h0);
        h1 = h2max0(h1);
        lg = hdot2(h0, w2h[mt][0], lg);
        lg = hdot2(h1, w2h[mt][1], lg);
      }
      s_lg4[pcur * 4 + kq] = (__fp16)lg;      // per-kq partial
      if (kq == 0) s_pool[pcur] = accp[0];    // pooled (MFMA k-reduced)

      t = tn;
      if (t >= NTILE) break;
      pcur = t * 16 + c;
    }
  }
#undef LDW1

  __syncthreads();

  // ---- phase 2: sum kq partials, softmax, weighted pool, line_out ----
  float* s_logit = (float*)s_pij;             // alias: pij dead now
  float m = -1e30f;
  for (int p = tid; p < NP; p += 256) {
    const half2t* lp = (const half2t*)&s_lg4[p * 4];
    half2t sfh = lp[0] + lp[1];
    float lg = (float)sfh[0] + (float)sfh[1];
    s_logit[p] = lg;
    m = fmaxf(m, lg);
  }
#pragma unroll
  for (int o = 32; o; o >>= 1) m = fmaxf(m, __shfl_xor(m, o, 64));
  if (lane == 0) s_red[wave] = m;
  __syncthreads();
  m = fmaxf(fmaxf(s_red[0], s_red[1]), fmaxf(s_red[2], s_red[3]));
  float se = 0.f, spe = 0.f;
  for (int p = tid; p < NP; p += 256) {
    float e = __expf(s_logit[p] - m);
    se += e;
    spe += e * s_pool[p];
  }
#pragma unroll
  for (int o = 32; o; o >>= 1) {
    se  += __shfl_xor(se, o, 64);
    spe += __shfl_xor(spe, o, 64);
  }
  if (lane == 0) { s_red[4 + wave] = se; s_red[8 + wave] = spe; }
  __syncthreads();
  if (tid == 0) {
    float line = blin[0];
#pragma unroll
    for (int f = 0; f < FN; ++f) line += s_wl[f];
    float SE  = s_red[4] + s_red[5] + s_red[6]  + s_red[7];
    float SPE = s_red[8] + s_red[9] + s_red[10] + s_red[11];
    out[b] = line + SPE / SE;
  }
}

extern "C" void kernel_launch(void* const* d_in, const int* in_sizes, int n_in,
                              void* d_out, int out_size, void* d_ws, size_t ws_size,
                              hipStream_t stream) {
  const int*   inp  = (const int*)d_in[0];
  const float* emb  = (const float*)d_in[1];
  const float* wlin = (const float*)d_in[2];
  const float* blin = (const float*)d_in[3];
  const float* W1   = (const float*)d_in[4];
  const float* b1   = (const float*)d_in[5];
  const float* W2   = (const float*)d_in[6];
  const float* b2   = (const float*)d_in[7];
  float* outp = (float*)d_out;
  const int B = in_sizes[0] / FN;
  afm_kernel<<<B, 256, 0, stream>>>(inp, emb, wlin, blin, W1, b1, W2, b2, outp, 4);
}

// Round 10
// 44.650 us; speedup vs baseline: 1.3495x; 1.3495x over previous
//
#include <hip/hip_runtime.h>
#include <math.h>

#define FN 50
#define CARD 10000
#define NP 1225          // F*(F-1)/2
#define NTILE 77         // ceil(NP/16)
#define NPAD (NTILE*16)  // 1232
#define FSTRIDE 72       // halves per factor row (144 B)

typedef _Float16 half8 __attribute__((ext_vector_type(8)));
typedef __fp16 half2t __attribute__((ext_vector_type(2)));
typedef float floatx4 __attribute__((ext_vector_type(4)));

static __device__ __forceinline__ half2t h2max0(half2t v) {
  half2t r;
  r[0] = v[0] > (__fp16)0 ? v[0] : (__fp16)0;
  r[1] = v[1] > (__fp16)0 ? v[1] : (__fp16)0;
  return r;
}
static __device__ __forceinline__ float hdot2(half2t a, half2t b, float c) {
#if __has_builtin(__builtin_amdgcn_fdot2)
  return __builtin_amdgcn_fdot2(a, b, c, false);
#else
  return c + (float)a[0]*(float)b[0] + (float)a[1]*(float)b[1];
#endif
}

__global__ __launch_bounds__(256, 4)
void afm_kernel(const int* __restrict__ inp,
                const float* __restrict__ emb,
                const float* __restrict__ wlin,
                const float* __restrict__ blin,
                const float* __restrict__ W1,
                const float* __restrict__ b1,
                const float* __restrict__ W2,
                const float* __restrict__ b2,
                float* __restrict__ out,
                int nrep0, int nrep2)
{
  __shared__ __align__(16) _Float16 s_fac[FN][FSTRIDE];   // 7200 B
  __shared__ __align__(16) _Float16 s_w1[512 * 8];        // 8192 B, frag layout
  __shared__ __align__(16) unsigned s_pij[NPAD];          // 4928 B (aliased f32 logit in ph2)
  __shared__ __align__(16) __fp16 s_lg4[NPAD * 4];        // 9856 B, per-kq logit partials
  __shared__ float s_pool[NPAD];                          // 4928 B
  __shared__ float s_wl[FN];
  __shared__ float s_red[16];

  const int tid  = threadIdx.x;
  const int b    = blockIdx.x;
  const int lane = tid & 63;
  const int wave = tid >> 6;
  const int c    = lane & 15;
  const int kq   = lane >> 4;

  // ==== phase 0 (repeated nrep0 times; idempotent LDS writes) ====
  for (int r0 = 0; r0 < nrep0; ++r0) {
    // 0a: pair table (closed form + fixup)
    for (int p = tid; p < NPAD; p += 256) {
      int pp = p < NP ? p : NP - 1;
      int i = (int)((99.0f - sqrtf(9801.0f - 8.0f * (float)pp)) * 0.5f);
      if (i < 0) i = 0;
      while ((i + 1) * (98 - i) / 2 <= pp) ++i;
      while (i > 0 && i * (99 - i) / 2 > pp) --i;
      int j = pp - i * (99 - i) / 2 + i + 1;
      s_pij[p] = (unsigned)(i * (FSTRIDE * 2)) | ((unsigned)(j * (FSTRIDE * 2)) << 16);
    }
    // 0b: factor gather f32 -> f16 LDS
    const int* inprow = inp + b * FN;
    for (int idx = tid; idx < FN * 16; idx += 256) {
      int f = idx >> 4, q = idx & 15;
      int flat = inprow[f] + f * CARD;
      floatx4 v = ((const floatx4*)emb)[(long)flat * 16 + q];
      _Float16* dst = &s_fac[f][q * 4];
      dst[0] = (_Float16)v[0]; dst[1] = (_Float16)v[1];
      dst[2] = (_Float16)v[2]; dst[3] = (_Float16)v[3];
    }
    if (tid < FN) {
      int flat = inprow[tid] + tid * CARD;
      s_wl[tid] = wlin[flat];
    }
    // 0c: stage W1 into LDS in fragment layout
    for (int ch = tid; ch < 512; ch += 256) {
      int ks = ch >> 8, mt = (ch >> 6) & 3, ln = ch & 63;
      int cc = ln & 15, kk = ln >> 4;
      _Float16 tmp[8];
#pragma unroll
      for (int j = 0; j < 8; ++j)
        tmp[j] = (_Float16)W1[(ks * 32 + kk * 8 + j) * 64 + mt * 16 + cc];
      *(half8*)&s_w1[ch * 8] = *(const half8*)tmp;
    }
  }

  // per-lane bias (f32, MFMA C-in) and W2 slice (f16 packed) — not repeated (registers)
  floatx4 bias[4];
  half2t w2h[4][2];
#pragma unroll
  for (int mt = 0; mt < 4; ++mt) {
    bias[mt] = ((const floatx4*)b1)[mt * 4 + kq];
    floatx4 wv = ((const floatx4*)W2)[mt * 4 + kq];
    w2h[mt][0] = __builtin_amdgcn_cvt_pkrtz(wv[0], wv[1]);
    w2h[mt][1] = __builtin_amdgcn_cvt_pkrtz(wv[2], wv[3]);
  }
  _Float16 onev = (c == 0) ? (_Float16)1 : (_Float16)0;
  half8 onesf = {onev, onev, onev, onev, onev, onev, onev, onev};

  __syncthreads();

  // ==== phase 1 (×1, identical to the 24.8 µs r4 kernel) ====
#define LDW1(ks, mt) (*(const half8*)&s_w1[(((ks) * 4 + (mt)) * 64 + lane) * 8])
  const char* fbase = (const char*)&s_fac[0][0];
  const int koff = kq * 16;
  {
    int t = wave;
    int pcur = t * 16 + c;
    unsigned po = s_pij[pcur];
    int offi = (int)(po & 0xffffu) + koff;
    int offj = (int)(po >> 16) + koff;
    half8 cvi0 = *(const half8*)(fbase + offi);
    half8 cvj0 = *(const half8*)(fbase + offj);
    half8 cvi1 = *(const half8*)(fbase + offi + 64);
    half8 cvj1 = *(const half8*)(fbase + offj + 64);

    while (true) {
      int tn = t + 4;
      int pn = tn * 16 + c; if (pn > NPAD - 1) pn = NPAD - 1;
      unsigned pon = s_pij[pn];

      half8 pr0 = cvi0 * cvj0;
      half8 pr1 = cvi1 * cvj1;

      floatx4 acc[4];
#pragma unroll
      for (int mt = 0; mt < 4; ++mt) {
        acc[mt] = __builtin_amdgcn_mfma_f32_16x16x32_f16(LDW1(0, mt), pr0, bias[mt], 0, 0, 0);
        acc[mt] = __builtin_amdgcn_mfma_f32_16x16x32_f16(LDW1(1, mt), pr1, acc[mt], 0, 0, 0);
      }
      floatx4 accp = __builtin_amdgcn_mfma_f32_16x16x32_f16(onesf, pr0, (floatx4){0.f,0.f,0.f,0.f}, 0, 0, 0);
      accp = __builtin_amdgcn_mfma_f32_16x16x32_f16(onesf, pr1, accp, 0, 0, 0);

      int offi_n = (int)(pon & 0xffffu) + koff;
      int offj_n = (int)(pon >> 16) + koff;
      cvi0 = *(const half8*)(fbase + offi_n);
      cvj0 = *(const half8*)(fbase + offj_n);
      cvi1 = *(const half8*)(fbase + offi_n + 64);
      cvj1 = *(const half8*)(fbase + offj_n + 64);

      float lg = 0.f;
#pragma unroll
      for (int mt = 0; mt < 4; ++mt) {
        half2t h0 = __builtin_amdgcn_cvt_pkrtz(acc[mt][0], acc[mt][1]);
        half2t h1 = __builtin_amdgcn_cvt_pkrtz(acc[mt][2], acc[mt][3]);
        h0 = h2max0(h0);
        h1 = h2max0(h1);
        lg = hdot2(h0, w2h[mt][0], lg);
        lg = hdot2(h1, w2h[mt][1], lg);
      }
      s_lg4[pcur * 4 + kq] = (__fp16)lg;
      if (kq == 0) s_pool[pcur] = accp[0];

      t = tn;
      if (t >= NTILE) break;
      pcur = t * 16 + c;
    }
  }
#undef LDW1

  __syncthreads();

  // ==== phase 2 (repeated nrep2 times; idempotent) ====
  for (int r2 = 0; r2 < nrep2; ++r2) {
    float* s_logit = (float*)s_pij;           // alias: pij dead after phase 1
    float m = -1e30f;
    for (int p = tid; p < NP; p += 256) {
      const half2t* lp = (const half2t*)&s_lg4[p * 4];
      half2t sfh = lp[0] + lp[1];
      float lg = (float)sfh[0] + (float)sfh[1];
      s_logit[p] = lg;
      m = fmaxf(m, lg);
    }
#pragma unroll
    for (int o = 32; o; o >>= 1) m = fmaxf(m, __shfl_xor(m, o, 64));
    if (lane == 0) s_red[wave] = m;
    __syncthreads();
    m = fmaxf(fmaxf(s_red[0], s_red[1]), fmaxf(s_red[2], s_red[3]));
    float se = 0.f, spe = 0.f;
    for (int p = tid; p < NP; p += 256) {
      float e = __expf(s_logit[p] - m);
      se += e;
      spe += e * s_pool[p];
    }
#pragma unroll
    for (int o = 32; o; o >>= 1) {
      se  += __shfl_xor(se, o, 64);
      spe += __shfl_xor(spe, o, 64);
    }
    if (lane == 0) { s_red[4 + wave] = se; s_red[8 + wave] = spe; }
    __syncthreads();
    if (tid == 0) {
      float line = blin[0];
#pragma unroll
      for (int f = 0; f < FN; ++f) line += s_wl[f];
      float SE  = s_red[4] + s_red[5] + s_red[6]  + s_red[7];
      float SPE = s_red[8] + s_red[9] + s_red[10] + s_red[11];
      out[b] = line + SPE / SE;
    }
  }
}

extern "C" void kernel_launch(void* const* d_in, const int* in_sizes, int n_in,
                              void* d_out, int out_size, void* d_ws, size_t ws_size,
                              hipStream_t stream) {
  const int*   inp  = (const int*)d_in[0];
  const float* emb  = (const float*)d_in[1];
  const float* wlin = (const float*)d_in[2];
  const float* blin = (const float*)d_in[3];
  const float* W1   = (const float*)d_in[4];
  const float* b1   = (const float*)d_in[5];
  const float* W2   = (const float*)d_in[6];
  const float* b2   = (const float*)d_in[7];
  float* outp = (float*)d_out;
  const int B = in_sizes[0] / FN;
  afm_kernel<<<B, 256, 0, stream>>>(inp, emb, wlin, blin, W1, b1, W2, b2, outp, 4, 4);
}

// Round 11
// 24.084 us; speedup vs baseline: 2.5020x; 1.8540x over previous
//
#include <hip/hip_runtime.h>
#include <math.h>

#define FN 50
#define CARD 10000
#define NP 1225          // F*(F-1)/2
#define NTILE 77         // ceil(NP/16)
#define NPAD (NTILE*16)  // 1232
#define FSTRIDE 72       // halves per factor row (144 B)

typedef _Float16 half8 __attribute__((ext_vector_type(8)));
typedef __fp16 half2t __attribute__((ext_vector_type(2)));
typedef __fp16 half4t __attribute__((ext_vector_type(4)));
typedef float floatx4 __attribute__((ext_vector_type(4)));

static __device__ __forceinline__ half2t h2max0(half2t v) {
  half2t r;
  r[0] = v[0] > (__fp16)0 ? v[0] : (__fp16)0;
  r[1] = v[1] > (__fp16)0 ? v[1] : (__fp16)0;
  return r;
}
static __device__ __forceinline__ float hdot2(half2t a, half2t b, float c) {
#if __has_builtin(__builtin_amdgcn_fdot2)
  return __builtin_amdgcn_fdot2(a, b, c, false);
#else
  return c + (float)a[0]*(float)b[0] + (float)a[1]*(float)b[1];
#endif
}

__global__ __launch_bounds__(256, 4)
void afm_kernel(const int* __restrict__ inp,
                const float* __restrict__ emb,
                const float* __restrict__ wlin,
                const float* __restrict__ blin,
                const float* __restrict__ W1,
                const float* __restrict__ b1,
                const float* __restrict__ W2,
                const float* __restrict__ b2,
                float* __restrict__ out)
{
  __shared__ __align__(16) _Float16 s_fac[FN][FSTRIDE];   // 7200 B
  __shared__ __align__(16) _Float16 s_w1[512 * 8];        // 8192 B, frag layout
  __shared__ __align__(16) unsigned s_pij[NPAD];          // 4928 B
  __shared__ __align__(16) __fp16 s_lg4[NPAD * 4];        // 9856 B, per-kq logit partials
  __shared__ float s_pool[NPAD];                          // 4928 B
  __shared__ float s_wl[FN];
  __shared__ float s_red[8];

  const int tid  = threadIdx.x;
  const int b    = blockIdx.x;
  const int lane = tid & 63;
  const int wave = tid >> 6;
  const int c    = lane & 15;
  const int kq   = lane >> 4;

  // ---- phase 0a: pair table (closed form + fixup) ----
  for (int p = tid; p < NPAD; p += 256) {
    int pp = p < NP ? p : NP - 1;
    int i = (int)((99.0f - sqrtf(9801.0f - 8.0f * (float)pp)) * 0.5f);
    if (i < 0) i = 0;
    while ((i + 1) * (98 - i) / 2 <= pp) ++i;
    while (i > 0 && i * (99 - i) / 2 > pp) --i;
    int j = pp - i * (99 - i) / 2 + i + 1;
    s_pij[p] = (unsigned)(i * (FSTRIDE * 2)) | ((unsigned)(j * (FSTRIDE * 2)) << 16);
  }

  // ---- phase 0b: factor gather f32 -> f16 LDS (packed 8B writes) ----
  const int* inprow = inp + b * FN;
  for (int idx = tid; idx < FN * 16; idx += 256) {
    int f = idx >> 4, q = idx & 15;
    int flat = inprow[f] + f * CARD;
    floatx4 v = ((const floatx4*)emb)[(long)flat * 16 + q];
    half2t lo = __builtin_amdgcn_cvt_pkrtz(v[0], v[1]);
    half2t hi = __builtin_amdgcn_cvt_pkrtz(v[2], v[3]);
    half4t pk = {lo[0], lo[1], hi[0], hi[1]};
    *(half4t*)&s_fac[f][q * 4] = pk;
  }
  if (tid < FN) {
    int flat = inprow[tid] + tid * CARD;
    s_wl[tid] = wlin[flat];
  }

  // ---- phase 0c: stage W1 into LDS in fragment layout (pkrtz packed) ----
  for (int ch = tid; ch < 512; ch += 256) {
    int ks = ch >> 8, mt = (ch >> 6) & 3, ln = ch & 63;
    int cc = ln & 15, kk = ln >> 4;
    __fp16 tmp[8];
#pragma unroll
    for (int j = 0; j < 4; ++j) {
      float x = W1[(ks * 32 + kk * 8 + 2 * j)     * 64 + mt * 16 + cc];
      float y = W1[(ks * 32 + kk * 8 + 2 * j + 1) * 64 + mt * 16 + cc];
      half2t hw = __builtin_amdgcn_cvt_pkrtz(x, y);
      tmp[2 * j] = hw[0]; tmp[2 * j + 1] = hw[1];
    }
    *(half8*)&s_w1[ch * 8] = *(const half8*)tmp;
  }

  // per-lane bias (f32, MFMA C-in) and W2 slice (f16 packed)
  floatx4 bias[4];
  half2t w2h[4][2];
#pragma unroll
  for (int mt = 0; mt < 4; ++mt) {
    bias[mt] = ((const floatx4*)b1)[mt * 4 + kq];
    floatx4 wv = ((const floatx4*)W2)[mt * 4 + kq];
    w2h[mt][0] = __builtin_amdgcn_cvt_pkrtz(wv[0], wv[1]);
    w2h[mt][1] = __builtin_amdgcn_cvt_pkrtz(wv[2], wv[3]);
  }
  _Float16 onev = (c == 0) ? (_Float16)1 : (_Float16)0;
  half8 onesf = {onev, onev, onev, onev, onev, onev, onev, onev};

  __syncthreads();

  // ---- phase 1: pipelined pair tiles (identical to r4 champion) ----
#define LDW1(ks, mt) (*(const half8*)&s_w1[(((ks) * 4 + (mt)) * 64 + lane) * 8])
  const char* fbase = (const char*)&s_fac[0][0];
  const int koff = kq * 16;
  {
    int t = wave;
    int pcur = t * 16 + c;
    unsigned po = s_pij[pcur];
    int offi = (int)(po & 0xffffu) + koff;
    int offj = (int)(po >> 16) + koff;
    half8 cvi0 = *(const half8*)(fbase + offi);
    half8 cvj0 = *(const half8*)(fbase + offj);
    half8 cvi1 = *(const half8*)(fbase + offi + 64);
    half8 cvj1 = *(const half8*)(fbase + offj + 64);

    while (true) {
      int tn = t + 4;
      int pn = tn * 16 + c; if (pn > NPAD - 1) pn = NPAD - 1;
      unsigned pon = s_pij[pn];

      half8 pr0 = cvi0 * cvj0;
      half8 pr1 = cvi1 * cvj1;

      floatx4 acc[4];
#pragma unroll
      for (int mt = 0; mt < 4; ++mt) {
        acc[mt] = __builtin_amdgcn_mfma_f32_16x16x32_f16(LDW1(0, mt), pr0, bias[mt], 0, 0, 0);
        acc[mt] = __builtin_amdgcn_mfma_f32_16x16x32_f16(LDW1(1, mt), pr1, acc[mt], 0, 0, 0);
      }
      floatx4 accp = __builtin_amdgcn_mfma_f32_16x16x32_f16(onesf, pr0, (floatx4){0.f,0.f,0.f,0.f}, 0, 0, 0);
      accp = __builtin_amdgcn_mfma_f32_16x16x32_f16(onesf, pr1, accp, 0, 0, 0);

      int offi_n = (int)(pon & 0xffffu) + koff;
      int offj_n = (int)(pon >> 16) + koff;
      cvi0 = *(const half8*)(fbase + offi_n);
      cvj0 = *(const half8*)(fbase + offj_n);
      cvi1 = *(const half8*)(fbase + offi_n + 64);
      cvj1 = *(const half8*)(fbase + offj_n + 64);

      float lg = 0.f;
#pragma unroll
      for (int mt = 0; mt < 4; ++mt) {
        half2t h0 = __builtin_amdgcn_cvt_pkrtz(acc[mt][0], acc[mt][1]);
        half2t h1 = __builtin_amdgcn_cvt_pkrtz(acc[mt][2], acc[mt][3]);
        h0 = h2max0(h0);
        h1 = h2max0(h1);
        lg = hdot2(h0, w2h[mt][0], lg);
        lg = hdot2(h1, w2h[mt][1], lg);
      }
      s_lg4[pcur * 4 + kq] = (__fp16)lg;
      if (kq == 0) s_pool[pcur] = accp[0];

      t = tn;
      if (t >= NTILE) break;
      pcur = t * 16 + c;
    }
  }
#undef LDW1

  __syncthreads();

  // ---- phase 2: single pass, max-free softmax (shift-invariant; |logit| << 1) ----
  float se = 0.f, spe = 0.f;
  for (int p = tid; p < NP; p += 256) {
    half4t v = *(const half4t*)&s_lg4[p * 4];    // one b64: 4 kq partials
    float lg = ((float)v[0] + (float)v[1]) + ((float)v[2] + (float)v[3]);
    float e = __expf(lg);
    se += e;
    spe += e * s_pool[p];
  }
#pragma unroll
  for (int o = 32; o; o >>= 1) {
    se  += __shfl_xor(se, o, 64);
    spe += __shfl_xor(spe, o, 64);
  }
  if (lane == 0) { s_red[wave] = se; s_red[4 + wave] = spe; }
  __syncthreads();
  if (tid == 0) {
    float line = blin[0];
#pragma unroll
    for (int f = 0; f < FN; ++f) line += s_wl[f];
    float SE  = s_red[0] + s_red[1] + s_red[2] + s_red[3];
    float SPE = s_red[4] + s_red[5] + s_red[6] + s_red[7];
    out[b] = line + SPE / SE;
  }
}

extern "C" void kernel_launch(void* const* d_in, const int* in_sizes, int n_in,
                              void* d_out, int out_size, void* d_ws, size_t ws_size,
                              hipStream_t stream) {
  const int*   inp  = (const int*)d_in[0];
  const float* emb  = (const float*)d_in[1];
  const float* wlin = (const float*)d_in[2];
  const float* blin = (const float*)d_in[3];
  const float* W1   = (const float*)d_in[4];
  const float* b1   = (const float*)d_in[5];
  const float* W2   = (const float*)d_in[6];
  const float* b2   = (const float*)d_in[7];
  float* outp = (float*)d_out;
  const int B = in_sizes[0] / FN;
  afm_kernel<<<B, 256, 0, stream>>>(inp, emb, wlin, blin, W1, b1, W2, b2, outp);
}

// Round 12
// 23.999 us; speedup vs baseline: 2.5108x; 1.0035x over previous
//
#include <hip/hip_runtime.h>
#include <math.h>

#define FN 50
#define CARD 10000
#define NP 1225          // F*(F-1)/2
#define NTILE 77         // ceil(NP/16)
#define NPAD (NTILE*16)  // 1232
#define FSTRIDE 72       // halves per factor row (144 B)

typedef _Float16 half8 __attribute__((ext_vector_type(8)));
typedef __fp16 half2t __attribute__((ext_vector_type(2)));
typedef __fp16 half4t __attribute__((ext_vector_type(4)));
typedef float floatx4 __attribute__((ext_vector_type(4)));

static __device__ __forceinline__ half2t h2max0(half2t v) {
  half2t r;
  r[0] = v[0] > (__fp16)0 ? v[0] : (__fp16)0;
  r[1] = v[1] > (__fp16)0 ? v[1] : (__fp16)0;
  return r;
}
static __device__ __forceinline__ float hdot2(half2t a, half2t b, float c) {
#if __has_builtin(__builtin_amdgcn_fdot2)
  return __builtin_amdgcn_fdot2(a, b, c, false);
#else
  return c + (float)a[0]*(float)b[0] + (float)a[1]*(float)b[1];
#endif
}

__global__ __launch_bounds__(256, 4)
void afm_kernel(const int* __restrict__ inp,
                const float* __restrict__ emb,
                const float* __restrict__ wlin,
                const float* __restrict__ blin,
                const float* __restrict__ W1,
                const float* __restrict__ b1,
                const float* __restrict__ W2,
                const float* __restrict__ b2,
                float* __restrict__ out)
{
  __shared__ __align__(16) _Float16 s_fac[FN][FSTRIDE];   // 7200 B
  __shared__ __align__(16) _Float16 s_w1[512 * 8];        // 8192 B, frag layout
  __shared__ __align__(16) unsigned s_pij[NPAD];          // 4928 B
  __shared__ float s_wl[FN];
  __shared__ float s_red[8];

  const int tid  = threadIdx.x;
  const int b    = blockIdx.x;
  const int lane = tid & 63;
  const int wave = tid >> 6;
  const int c    = lane & 15;
  const int kq   = lane >> 4;

  // ---- phase 0a: pair table (closed form + fixup) ----
  for (int p = tid; p < NPAD; p += 256) {
    int pp = p < NP ? p : NP - 1;
    int i = (int)((99.0f - sqrtf(9801.0f - 8.0f * (float)pp)) * 0.5f);
    if (i < 0) i = 0;
    while ((i + 1) * (98 - i) / 2 <= pp) ++i;
    while (i > 0 && i * (99 - i) / 2 > pp) --i;
    int j = pp - i * (99 - i) / 2 + i + 1;
    s_pij[p] = (unsigned)(i * (FSTRIDE * 2)) | ((unsigned)(j * (FSTRIDE * 2)) << 16);
  }

  // ---- phase 0b: factor gather f32 -> f16 LDS (packed 8B writes) ----
  const int* inprow = inp + b * FN;
  for (int idx = tid; idx < FN * 16; idx += 256) {
    int f = idx >> 4, q = idx & 15;
    int flat = inprow[f] + f * CARD;
    floatx4 v = ((const floatx4*)emb)[(long)flat * 16 + q];
    half2t lo = __builtin_amdgcn_cvt_pkrtz(v[0], v[1]);
    half2t hi = __builtin_amdgcn_cvt_pkrtz(v[2], v[3]);
    half4t pk = {lo[0], lo[1], hi[0], hi[1]};
    *(half4t*)&s_fac[f][q * 4] = pk;
  }
  if (tid < FN) {
    int flat = inprow[tid] + tid * CARD;
    s_wl[tid] = wlin[flat];
  }

  // ---- phase 0c: stage W1 into LDS in fragment layout (pkrtz packed) ----
  for (int ch = tid; ch < 512; ch += 256) {
    int ks = ch >> 8, mt = (ch >> 6) & 3, ln = ch & 63;
    int cc = ln & 15, kk = ln >> 4;
    __fp16 tmp[8];
#pragma unroll
    for (int j = 0; j < 4; ++j) {
      float x = W1[(ks * 32 + kk * 8 + 2 * j)     * 64 + mt * 16 + cc];
      float y = W1[(ks * 32 + kk * 8 + 2 * j + 1) * 64 + mt * 16 + cc];
      half2t hw = __builtin_amdgcn_cvt_pkrtz(x, y);
      tmp[2 * j] = hw[0]; tmp[2 * j + 1] = hw[1];
    }
    *(half8*)&s_w1[ch * 8] = *(const half8*)tmp;
  }

  // per-lane bias (f32, MFMA C-in) and W2 slice (f16 packed)
  floatx4 bias[4];
  half2t w2h[4][2];
#pragma unroll
  for (int mt = 0; mt < 4; ++mt) {
    bias[mt] = ((const floatx4*)b1)[mt * 4 + kq];
    floatx4 wv = ((const floatx4*)W2)[mt * 4 + kq];
    w2h[mt][0] = __builtin_amdgcn_cvt_pkrtz(wv[0], wv[1]);
    w2h[mt][1] = __builtin_amdgcn_cvt_pkrtz(wv[2], wv[3]);
  }
  _Float16 onev = (c == 0) ? (_Float16)1 : (_Float16)0;
  half8 onesf = {onev, onev, onev, onev, onev, onev, onev, onev};

  __syncthreads();

  // ---- phase 1: pipelined tiles; pij 2-deep prefetch; fused softmax accumulate ----
#define LDW1(ks, mt) (*(const half8*)&s_w1[(((ks) * 4 + (mt)) * 64 + lane) * 8])
  const char* fbase = (const char*)&s_fac[0][0];
  const int koff = kq * 16;
  float se = 0.f, spe = 0.f;
  {
    int t = wave;
    int pcur = t * 16 + c;
    unsigned po_cur = s_pij[pcur];
    int pn1 = (t + 4) * 16 + c; if (pn1 > NPAD - 1) pn1 = NPAD - 1;
    unsigned po_nx = s_pij[pn1];                 // 1 ahead (for factor prefetch)
    int offi = (int)(po_cur & 0xffffu) + koff;
    int offj = (int)(po_cur >> 16) + koff;
    half8 cvi0 = *(const half8*)(fbase + offi);
    half8 cvj0 = *(const half8*)(fbase + offj);
    half8 cvi1 = *(const half8*)(fbase + offi + 64);
    half8 cvj1 = *(const half8*)(fbase + offj + 64);

    while (true) {
      int pn2 = (t + 8) * 16 + c; if (pn2 > NPAD - 1) pn2 = NPAD - 1;
      unsigned po_n2 = s_pij[pn2];               // 2 ahead — latency hides over a full iter

      half8 pr0 = cvi0 * cvj0;                   // inter, k-slice 0
      half8 pr1 = cvi1 * cvj1;                   // k-slice 1

      floatx4 acc[4];
#pragma unroll
      for (int mt = 0; mt < 4; ++mt) {
        acc[mt] = __builtin_amdgcn_mfma_f32_16x16x32_f16(LDW1(0, mt), pr0, bias[mt], 0, 0, 0);
        acc[mt] = __builtin_amdgcn_mfma_f32_16x16x32_f16(LDW1(1, mt), pr1, acc[mt], 0, 0, 0);
      }
      floatx4 accp = __builtin_amdgcn_mfma_f32_16x16x32_f16(onesf, pr0, (floatx4){0.f,0.f,0.f,0.f}, 0, 0, 0);
      accp = __builtin_amdgcn_mfma_f32_16x16x32_f16(onesf, pr1, accp, 0, 0, 0);

      // factor prefetch for t+4 using po_nx (read issued a full iteration ago)
      int offi_n = (int)(po_nx & 0xffffu) + koff;
      int offj_n = (int)(po_nx >> 16) + koff;
      cvi0 = *(const half8*)(fbase + offi_n);
      cvj0 = *(const half8*)(fbase + offj_n);
      cvi1 = *(const half8*)(fbase + offi_n + 64);
      cvj1 = *(const half8*)(fbase + offj_n + 64);

      // epilogue: relu (bias in acc) + W2 dot, f16-packed
      float lg = 0.f;
#pragma unroll
      for (int mt = 0; mt < 4; ++mt) {
        half2t h0 = __builtin_amdgcn_cvt_pkrtz(acc[mt][0], acc[mt][1]);
        half2t h1 = __builtin_amdgcn_cvt_pkrtz(acc[mt][2], acc[mt][3]);
        h0 = h2max0(h0);
        h1 = h2max0(h1);
        lg = hdot2(h0, w2h[mt][0], lg);
        lg = hdot2(h1, w2h[mt][1], lg);
      }
      // fused max-free softmax accumulation (off the critical path)
      lg += __shfl_xor(lg, 16, 64);              // sum the 4 kq partials
      lg += __shfl_xor(lg, 32, 64);
      float e = __expf(lg);
      if (kq == 0 && pcur < NP) {                // mask clamped tail pairs
        se  += e;
        spe += e * accp[0];                      // ones-MFMA row 0 = pooled[pcur]
      }

      t += 4;
      if (t >= NTILE) break;
      pcur = t * 16 + c;
      po_nx = po_n2;
    }
  }
#undef LDW1

  // reduce se/spe across lanes 0..15 (kq==0 lanes hold partials; xor<16 stays in group)
#pragma unroll
  for (int o = 1; o <= 8; o <<= 1) {
    se  += __shfl_xor(se, o, 64);
    spe += __shfl_xor(spe, o, 64);
  }
  if (lane == 0) { s_red[wave] = se; s_red[4 + wave] = spe; }
  __syncthreads();
  if (tid == 0) {
    float line = blin[0];
#pragma unroll
    for (int f = 0; f < FN; ++f) line += s_wl[f];
    float SE  = s_red[0] + s_red[1] + s_red[2] + s_red[3];
    float SPE = s_red[4] + s_red[5] + s_red[6] + s_red[7];
    out[b] = line + SPE / SE;
  }
}

extern "C" void kernel_launch(void* const* d_in, const int* in_sizes, int n_in,
                              void* d_out, int out_size, void* d_ws, size_t ws_size,
                              hipStream_t stream) {
  const int*   inp  = (const int*)d_in[0];
  const float* emb  = (const float*)d_in[1];
  const float* wlin = (const float*)d_in[2];
  const float* blin = (const float*)d_in[3];
  const float* W1   = (const float*)d_in[4];
  const float* b1   = (const float*)d_in[5];
  const float* W2   = (const float*)d_in[6];
  const float* b2   = (const float*)d_in[7];
  float* outp = (float*)d_out;
  const int B = in_sizes[0] / FN;
  afm_kernel<<<B, 256, 0, stream>>>(inp, emb, wlin, blin, W1, b1, W2, b2, outp);
}